// Round 10
// baseline (120.498 us; speedup 1.0000x reference)
//
#include <hip/hip_runtime.h>

#define BB 64
#define SS 512
#define DD 768
#define TT 9
#define CC 64   // chunks per batch (CRF)
#define LL 8    // CRF chunk length
#define NBLK 512
#define RPW 16  // rows per wave in phase A

// DPP reduction: row_shr 1/2/4/8 + row_bcast15/31 -> lane 63 holds wave sum.
template <int CTRL>
__device__ __forceinline__ float dpp_radd(float v) {
  return v + __int_as_float(__builtin_amdgcn_update_dpp(
                 0, __float_as_int(v), CTRL, 0xF, 0xF, true));
}
__device__ __forceinline__ float wave_sum_dpp(float v) {
  v = dpp_radd<0x111>(v);
  v = dpp_radd<0x112>(v);
  v = dpp_radd<0x114>(v);
  v = dpp_radd<0x118>(v);
  v = dpp_radd<0x142>(v);
  v = dpp_radd<0x143>(v);
  return v;  // valid in lane 63
}

// ---------------------------------------------------------------------------
// Single fused kernel. 512 blocks x 256 thr, __launch_bounds__(256,2) ->
// all blocks co-resident (2/CU, LDS 50KB, VGPR forced <=256).
// Phase A: emissions GEMV, wave-per-row (DPP reduce), 16 rows/wave.
// Device barrier: device-scope atomicAdd + acquire spin (all resident).
// Phase B (blocks 0..63): per-batch CRF chunk products + tree combine + num.
// Finalize: last of 64 blocks sums partials in fixed order -> mean.
// ---------------------------------------------------------------------------
__global__ __launch_bounds__(256, 2) void bertcrf_fused(
    const float* __restrict__ embeds, const float* __restrict__ weight,
    const float* __restrict__ bias, const float* __restrict__ startt,
    const float* __restrict__ endt, const float* __restrict__ trans,
    const int* __restrict__ tags, float* __restrict__ emis,
    float* __restrict__ partial, int* __restrict__ ctr,
    float* __restrict__ out) {
  const int tid  = threadIdx.x;
  const int lane = tid & 63;
  const int wv   = tid >> 6;

  __shared__ float em[SS * TT];        // 18432 B (phase B)
  __shared__ float cm[CC * 81];        // 20736 B
  __shared__ float Bm[(CC / 2) * 81];  // 10368 B
  __shared__ float trl[81], etl[81];
  __shared__ float red2[4];

  // ================= phase A: emissions =================
  {
    float w[TT][12];
#pragma unroll
    for (int t = 0; t < TT; ++t) {
#pragma unroll
      for (int k = 0; k < 3; ++k) {
        const float4 v = *(const float4*)(weight + t * DD + k * 256 + lane * 4);
        w[t][k * 4 + 0] = v.x; w[t][k * 4 + 1] = v.y;
        w[t][k * 4 + 2] = v.z; w[t][k * 4 + 3] = v.w;
      }
    }
    float bb[TT];
#pragma unroll
    for (int t = 0; t < TT; ++t) bb[t] = bias[t];

    const int wid = blockIdx.x * 4 + wv;  // 0..2047
#pragma unroll 2
    for (int r = 0; r < RPW; ++r) {
      const int row = wid * RPW + r;
      const float* ep = embeds + (size_t)row * DD;
      float e[12];
#pragma unroll
      for (int k = 0; k < 3; ++k) {
        const float4 v = *(const float4*)(ep + k * 256 + lane * 4);
        e[k * 4 + 0] = v.x; e[k * 4 + 1] = v.y;
        e[k * 4 + 2] = v.z; e[k * 4 + 3] = v.w;
      }
      float acc[TT];
#pragma unroll
      for (int t = 0; t < TT; ++t) {
        float a = 0.f;
#pragma unroll
        for (int kk = 0; kk < 12; ++kk) a = fmaf(e[kk], w[t][kk], a);
        acc[t] = wave_sum_dpp(a);
      }
      if (lane == 63) {
#pragma unroll
        for (int t = 0; t < TT; ++t)
          emis[(size_t)row * TT + t] = acc[t] + bb[t];
      }
    }
  }

  // ================= device-wide barrier =================
  __syncthreads();
  __threadfence();  // publish this block's emis rows (device scope)
  if (tid == 0) __hip_atomic_fetch_add(&ctr[0], 1, __ATOMIC_ACQ_REL,
                                       __HIP_MEMORY_SCOPE_AGENT);
  if (blockIdx.x >= BB) return;  // workers done

  if (tid == 0) {
    while (__hip_atomic_load(&ctr[0], __ATOMIC_ACQUIRE,
                             __HIP_MEMORY_SCOPE_AGENT) < NBLK) {
    }
  }
  __syncthreads();
  __threadfence();  // acquire: invalidate stale cache before reading emis

  // ================= phase B: per-batch CRF =================
  const int b = blockIdx.x;
  if (tid < 81) {
    const float tv = trans[tid];
    trl[tid] = tv;
    etl[tid] = __expf(tv);
  }
  {  // stage emis[b] into LDS
    const float4* e0 = (const float4*)(emis + (size_t)b * SS * TT);
    float4* em4 = (float4*)em;
    for (int q = tid; q < (SS * TT) / 4; q += 256) em4[q] = e0[q];
  }
  __syncthreads();

  // numerator partials (mask all-true)
  const int* tg = tags + (size_t)b * SS;
  float nsum = 0.f;
  for (int s = tid; s < SS; s += 256) {
    const int tt = tg[s];
    float term = em[s * TT + tt];
    term += (s == 0) ? startt[tt] : trl[tg[s - 1] * TT + tt];
    nsum += term;
  }
  nsum = wave_sum_dpp(nsum);
  if ((tid & 63) == 63) red2[tid >> 6] = nsum;

  // chunk column products: task (c = task/9, j = task%9)
  for (int task = tid; task < CC * TT; task += 256) {
    const int c = task / TT, j = task - (task / TT) * TT;
    const float* e = em + c * (LL * TT);
    float v[TT];
#pragma unroll
    for (int i = 0; i < TT; ++i) v[i] = trl[i * TT + j] + e[(LL - 1) * TT + j];
#pragma unroll
    for (int ss = LL - 2; ss >= 0; --ss) {
      float x[TT];
#pragma unroll
      for (int k = 0; k < TT; ++k) x[k] = e[ss * TT + k] + v[k];
      if (ss == 0 && c == 0) {  // batch's s==0: rank-1 start fold
#pragma unroll
        for (int k = 0; k < TT; ++k) x[k] += startt[k];
        float m = x[0];
#pragma unroll
        for (int k = 1; k < TT; ++k) m = fmaxf(m, x[k]);
        float sum = 0.f;
#pragma unroll
        for (int k = 0; k < TT; ++k) sum += __expf(x[k] - m);
        const float val = m + __logf(sum);
#pragma unroll
        for (int i = 0; i < TT; ++i) v[i] = val;
      } else {
        float m = x[0];
#pragma unroll
        for (int k = 1; k < TT; ++k) m = fmaxf(m, x[k]);
        float p[TT];
#pragma unroll
        for (int k = 0; k < TT; ++k) p[k] = __expf(x[k] - m);
#pragma unroll
        for (int i = 0; i < TT; ++i) {
          float sum = 0.f;
#pragma unroll
          for (int k = 0; k < TT; ++k) sum = fmaf(etl[i * TT + k], p[k], sum);
          v[i] = m + __logf(sum);
        }
      }
    }
#pragma unroll
    for (int i = 0; i < TT; ++i) cm[c * 81 + j * TT + i] = v[i];
  }
  __syncthreads();

  // tree combine (6 levels)
  float* srcb = cm;
  float* dstb = Bm;
  for (int n = CC / 2; n >= 1; n >>= 1) {
    for (int task = tid; task < n * TT; task += 256) {
      const int p = task / TT, j = task - (task / TT) * TT;
      float a[81], wvv[TT];
      const float* AT = srcb + (2 * p) * 81;
      const float* BT = srcb + (2 * p + 1) * 81;
#pragma unroll
      for (int q = 0; q < 81; ++q) a[q] = AT[q];
#pragma unroll
      for (int k = 0; k < TT; ++k) wvv[k] = BT[j * TT + k];
      float* OT = dstb + p * 81;
#pragma unroll
      for (int i = 0; i < TT; ++i) {
        float x[TT];
#pragma unroll
        for (int k = 0; k < TT; ++k) x[k] = a[k * TT + i] + wvv[k];
        float m = x[0];
#pragma unroll
        for (int k = 1; k < TT; ++k) m = fmaxf(m, x[k]);
        float sum = 0.f;
#pragma unroll
        for (int k = 0; k < TT; ++k) sum += __expf(x[k] - m);
        OT[j * TT + i] = m + __logf(sum);
      }
    }
    __syncthreads();
    float* tmp = srcb; srcb = dstb; dstb = tmp;
  }

  // finalize
  if (tid == 0) {
    float num = red2[0] + red2[1] + red2[2] + red2[3];
    num += endt[tg[SS - 1]];

    float x[TT];
#pragma unroll
    for (int j = 0; j < TT; ++j) x[j] = srcb[j * TT + 0] + endt[j];
    float m = x[0];
#pragma unroll
    for (int j = 1; j < TT; ++j) m = fmaxf(m, x[j]);
    float sum = 0.f;
#pragma unroll
    for (int j = 0; j < TT; ++j) sum += __expf(x[j] - m);
    partial[b] = (m + __logf(sum)) - num;

    __threadfence();  // publish partial[b]
    const int old = __hip_atomic_fetch_add(&ctr[1], 1, __ATOMIC_ACQ_REL,
                                           __HIP_MEMORY_SCOPE_AGENT);
    if (old == BB - 1) {
      __threadfence();
      volatile const float* vp = partial;
      float s = 0.f;
#pragma unroll
      for (int i = 0; i < BB; ++i) s += vp[i];  // fixed order: deterministic
      out[0] = s * (1.0f / BB);
    }
  }
}

extern "C" void kernel_launch(void* const* d_in, const int* in_sizes, int n_in,
                              void* d_out, int out_size, void* d_ws, size_t ws_size,
                              hipStream_t stream) {
  const float* embeds = (const float*)d_in[0];
  const float* weight = (const float*)d_in[1];
  const float* bias   = (const float*)d_in[2];
  const float* startt = (const float*)d_in[3];
  const float* endt   = (const float*)d_in[4];
  const float* trans  = (const float*)d_in[5];
  const int*   tags   = (const int*)d_in[6];

  float* ws      = (float*)d_ws;
  float* emis    = ws;                           // B*S*T floats
  float* partial = emis + (size_t)BB * SS * TT;  // B floats
  int*   ctr     = (int*)(partial + BB);         // 2 ints (barrier, finalize)
  float* out     = (float*)d_out;

  hipMemsetAsync(ctr, 0, 2 * sizeof(int), stream);  // capture-legal memset node
  bertcrf_fused<<<NBLK, 256, 0, stream>>>(embeds, weight, bias, startt, endt,
                                          trans, tags, emis, partial, ctr, out);
}

// Round 11
// 57.080 us; speedup vs baseline: 2.1110x; 2.1110x over previous
//
#include <hip/hip_runtime.h>

#define BB 64
#define SS 512
#define DD 768
#define TT 9
#define CC 64   // chunks per batch (CRF)
#define LL 8    // CRF chunk length

// DPP reduction: row_shr 1/2/4/8 + row_bcast15/31 -> lane 63 holds wave sum.
template <int CTRL>
__device__ __forceinline__ float dpp_radd(float v) {
  return v + __int_as_float(__builtin_amdgcn_update_dpp(
                 0, __float_as_int(v), CTRL, 0xF, 0xF, true));
}
__device__ __forceinline__ float wave_sum_dpp(float v) {
  v = dpp_radd<0x111>(v);
  v = dpp_radd<0x112>(v);
  v = dpp_radd<0x114>(v);
  v = dpp_radd<0x118>(v);
  v = dpp_radd<0x142>(v);
  v = dpp_radd<0x143>(v);
  return v;  // valid in lane 63
}

// ---------------------------------------------------------------------------
// Kernel A: emissions (R3-exact config — best measured: ~3.7 TB/s read,
// at the demonstrated streaming-read ceiling). Wave-per-row, 1KB-contiguous
// wave loads, weights in VGPRs, DPP reduce, lane-63 stores.
// ---------------------------------------------------------------------------
__global__ __launch_bounds__(256) void emis_kernel(
    const float* __restrict__ embeds, const float* __restrict__ weight,
    const float* __restrict__ bias, float* __restrict__ emis) {
  const int lane = threadIdx.x & 63;
  const int wave = blockIdx.x * (blockDim.x >> 6) + (threadIdx.x >> 6);
  const int nwav = gridDim.x * (blockDim.x >> 6);

  float w[TT][12];
#pragma unroll
  for (int t = 0; t < TT; ++t) {
#pragma unroll
    for (int k = 0; k < 3; ++k) {
      const float4 v = *(const float4*)(weight + t * DD + k * 256 + lane * 4);
      w[t][k * 4 + 0] = v.x; w[t][k * 4 + 1] = v.y;
      w[t][k * 4 + 2] = v.z; w[t][k * 4 + 3] = v.w;
    }
  }
  float bb[TT];
#pragma unroll
  for (int t = 0; t < TT; ++t) bb[t] = bias[t];

  for (int row = wave; row < BB * SS; row += nwav) {
    const float* ep = embeds + (size_t)row * DD;
    float e[12];
#pragma unroll
    for (int k = 0; k < 3; ++k) {
      const float4 v = *(const float4*)(ep + k * 256 + lane * 4);
      e[k * 4 + 0] = v.x; e[k * 4 + 1] = v.y;
      e[k * 4 + 2] = v.z; e[k * 4 + 3] = v.w;
    }
    float acc[TT];
#pragma unroll
    for (int t = 0; t < TT; ++t) {
      float a = 0.f;
#pragma unroll
      for (int kk = 0; kk < 12; ++kk) a = fmaf(e[kk], w[t][kk], a);
      acc[t] = wave_sum_dpp(a);
    }
    if (lane == 63) {
#pragma unroll
      for (int t = 0; t < TT; ++t)
        emis[(size_t)row * TT + t] = acc[t] + bb[t];
    }
  }
}

// ---------------------------------------------------------------------------
// Kernel B: fused per-batch CRF (R9-verified structure). Stage emis[b] in
// LDS, numerator + 64 chunk column-products (576 thr = 64 chunks x 9 cols),
// LDS tree-combine, last-block finalize -> mean.
// ---------------------------------------------------------------------------
__global__ __launch_bounds__(576) void crf_fused_kernel(
    const float* __restrict__ emis, const float* __restrict__ trans,
    const float* __restrict__ startt, const float* __restrict__ endt,
    const int* __restrict__ tags, float* __restrict__ partial,
    int* __restrict__ ctr, float* __restrict__ out) {
  const int b   = blockIdx.x;
  const int tid = threadIdx.x;
  __shared__ float em[SS * TT];        // 18432 B
  __shared__ float cm[CC * 81];        // 20736 B
  __shared__ float Bm[(CC / 2) * 81];  // 10368 B
  __shared__ float trl[81], etl[81];
  __shared__ float red2[12];

  if (tid < 81) {
    const float tv = trans[tid];
    trl[tid] = tv;
    etl[tid] = __expf(tv);
  }
  {  // stage emis[b] (float4)
    const float4* e0 = (const float4*)(emis + (size_t)b * SS * TT);
    float4* em4 = (float4*)em;
#pragma unroll
    for (int q = tid; q < (SS * TT) / 4; q += 576) em4[q] = e0[q];
  }
  __syncthreads();

  // ---- numerator partial (mask all-true); emis from LDS ----
  const int* tg = tags + (size_t)b * SS;
  float nsum = 0.f;
  if (tid < SS) {
    const int tt = tg[tid];
    nsum = em[tid * TT + tt];
    nsum += (tid == 0) ? startt[tt] : trl[tg[tid - 1] * TT + tt];
  }
  nsum = wave_sum_dpp(nsum);
  if ((tid & 63) == 63) red2[tid >> 6] = nsum;

  // ---- chunk column products: task (c = tid/9, j = tid%9) ----
  {
    const int c = tid / TT, j = tid - (tid / TT) * TT;
    const float* e = em + c * (LL * TT);
    float v[TT];
#pragma unroll
    for (int i = 0; i < TT; ++i) v[i] = trl[i * TT + j] + e[(LL - 1) * TT + j];
#pragma unroll
    for (int ss = LL - 2; ss >= 0; --ss) {
      float x[TT];
#pragma unroll
      for (int k = 0; k < TT; ++k) x[k] = e[ss * TT + k] + v[k];
      if (ss == 0 && c == 0) {  // batch's s==0: rank-1 start fold
#pragma unroll
        for (int k = 0; k < TT; ++k) x[k] += startt[k];
        float m = x[0];
#pragma unroll
        for (int k = 1; k < TT; ++k) m = fmaxf(m, x[k]);
        float sum = 0.f;
#pragma unroll
        for (int k = 0; k < TT; ++k) sum += __expf(x[k] - m);
        const float val = m + __logf(sum);
#pragma unroll
        for (int i = 0; i < TT; ++i) v[i] = val;
      } else {
        float m = x[0];
#pragma unroll
        for (int k = 1; k < TT; ++k) m = fmaxf(m, x[k]);
        float p[TT];
#pragma unroll
        for (int k = 0; k < TT; ++k) p[k] = __expf(x[k] - m);
#pragma unroll
        for (int i = 0; i < TT; ++i) {
          float sum = 0.f;
#pragma unroll
          for (int k = 0; k < TT; ++k) sum = fmaf(etl[i * TT + k], p[k], sum);
          v[i] = m + __logf(sum);
        }
      }
    }
#pragma unroll
    for (int i = 0; i < TT; ++i) cm[c * 81 + j * TT + i] = v[i];
  }
  __syncthreads();

  // ---- tree combine (6 levels) ----
  float* srcb = cm;
  float* dstb = Bm;
  for (int n = CC / 2; n >= 1; n >>= 1) {
    if (tid < n * TT) {
      const int p = tid / TT, j = tid - (tid / TT) * TT;
      float a[81], wvv[TT];
      const float* AT = srcb + (2 * p) * 81;
      const float* BT = srcb + (2 * p + 1) * 81;
#pragma unroll
      for (int q = 0; q < 81; ++q) a[q] = AT[q];
#pragma unroll
      for (int k = 0; k < TT; ++k) wvv[k] = BT[j * TT + k];
      float* OT = dstb + p * 81;
#pragma unroll
      for (int i = 0; i < TT; ++i) {
        float x[TT];
#pragma unroll
        for (int k = 0; k < TT; ++k) x[k] = a[k * TT + i] + wvv[k];
        float m = x[0];
#pragma unroll
        for (int k = 1; k < TT; ++k) m = fmaxf(m, x[k]);
        float sum = 0.f;
#pragma unroll
        for (int k = 0; k < TT; ++k) sum += __expf(x[k] - m);
        OT[j * TT + i] = m + __logf(sum);
      }
    }
    __syncthreads();
    float* tmp = srcb; srcb = dstb; dstb = tmp;
  }

  // ---- finalize ----
  if (tid == 0) {
    float num = red2[0];
#pragma unroll
    for (int w = 1; w < 9; ++w) num += red2[w];
    num += endt[tg[SS - 1]];

    float x[TT];
#pragma unroll
    for (int j = 0; j < TT; ++j) x[j] = srcb[j * TT + 0] + endt[j];
    float m = x[0];
#pragma unroll
    for (int j = 1; j < TT; ++j) m = fmaxf(m, x[j]);
    float sum = 0.f;
#pragma unroll
    for (int j = 0; j < TT; ++j) sum += __expf(x[j] - m);
    partial[b] = (m + __logf(sum)) - num;

    __threadfence();                    // publish partial[b]
    const int old = atomicAdd(ctr, 1);  // device-scope
    if (old == BB - 1) {
      __threadfence();                  // acquire all partials
      volatile const float* vp = partial;
      float s = 0.f;
#pragma unroll
      for (int i = 0; i < BB; ++i) s += vp[i];  // fixed order: deterministic
      out[0] = s * (1.0f / BB);
    }
  }
}

extern "C" void kernel_launch(void* const* d_in, const int* in_sizes, int n_in,
                              void* d_out, int out_size, void* d_ws, size_t ws_size,
                              hipStream_t stream) {
  const float* embeds = (const float*)d_in[0];
  const float* weight = (const float*)d_in[1];
  const float* bias   = (const float*)d_in[2];
  const float* startt = (const float*)d_in[3];
  const float* endt   = (const float*)d_in[4];
  const float* trans  = (const float*)d_in[5];
  const int*   tags   = (const int*)d_in[6];

  float* ws      = (float*)d_ws;
  float* emis    = ws;                           // B*S*T floats
  float* partial = emis + (size_t)BB * SS * TT;  // B floats
  int*   ctr     = (int*)(partial + BB);         // 1 int
  float* out     = (float*)d_out;

  hipMemsetAsync(ctr, 0, sizeof(int), stream);  // capture-legal memset node
  emis_kernel<<<2048, 256, 0, stream>>>(embeds, weight, bias, emis);
  crf_fused_kernel<<<BB, 576, 0, stream>>>(emis, trans, startt, endt, tags,
                                           partial, ctr, out);
}